// Round 14
// baseline (245.079 us; speedup 1.0000x reference)
//
#include <hip/hip_runtime.h>
#include <math.h>

// Problem constants
#define Bd   4
#define Md   8192
#define Dd   64
#define Sd   1024
#define H0d  32
#define H1d  128

// d_out layout (float offsets), return order:
// sampled_points (B,S,3) | grouped_points (B,S,32,3) | sampled_feature (B,S,64)
// | grouped_feature (B,S,32,64) | Qg (B,S,M)
#define OFF_SP 0
#define OFF_GP 12288
#define OFF_SF 405504
#define OFF_GF 667648          // holds f32 h1T scratch [b][k][m] (16.8MB) until k3 overwrites
#define OFF_QG 9056256         // holds f32 logits [B][S][M] until one-hot overwrite

#define CAP 512                // candidate cap (expected n ~150)

// order-preserving float -> sortable u32, and exact inverse
__device__ __forceinline__ unsigned f2u(float f) {
    unsigned v = __float_as_uint(f);
    return (v & 0x80000000u) ? ~v : (v | 0x80000000u);
}
__device__ __forceinline__ float u2f(unsigned u) {
    return __uint_as_float((u & 0x80000000u) ? (u ^ 0x80000000u) : ~u);
}

// ---------------------------------------------------------------------------
// K1: per-point MLP (f64 internal math, f32 output), h1T[b][k][m].
// 4-way j-split, 512 blocks — bitwise-identical h1T, verified rounds 10-13.
// ---------------------------------------------------------------------------
__global__ __launch_bounds__(256) void k1_mlp(
    const float* __restrict__ coord,
    const float* __restrict__ w0,
    const float* __restrict__ g0, const float* __restrict__ be0,
    const float* __restrict__ mu0, const float* __restrict__ va0,
    const float* __restrict__ w1,
    const float* __restrict__ g1, const float* __restrict__ be1,
    const float* __restrict__ mu1, const float* __restrict__ va1,
    float* __restrict__ h1T)
{
    const int jg = blockIdx.x & 3;           // j-range [jg*32, jg*32+32)
    const int j0 = jg * 32;
    __shared__ double W1[H0d * 32];
    __shared__ double W0[5 * H0d];
    __shared__ double MU0[H0d], RS0[H0d], BE0[H0d];
    __shared__ double MU1[32], RS1[32], BE1[32];
    const int t = threadIdx.x;
    for (int e = t; e < H0d * 32; e += 256) {
        int i = e >> 5, jc = e & 31;
        W1[e] = (double)w1[i * H1d + j0 + jc];
    }
    if (t < 5 * H0d) W0[t] = (double)w0[t];
    if (t < H0d) {
        MU0[t] = (double)mu0[t];
        RS0[t] = (double)g0[t] / sqrt((double)va0[t] + 1e-5);
        BE0[t] = (double)be0[t];
    }
    if (t >= 192 && t < 224) {
        int j = t - 192;
        MU1[j] = (double)mu1[j0 + j];
        RS1[j] = (double)g1[j0 + j] / sqrt((double)va1[j0 + j] + 1e-5);
        BE1[j] = (double)be1[j0 + j];
    }
    __syncthreads();

    const int p = (blockIdx.x >> 2) * 256 + t;   // 0..32767  (= b*M + m)
    const double x = (double)coord[p * 3 + 0];
    const double y = (double)coord[p * 3 + 1];
    const double z = (double)coord[p * 3 + 2];
    const double r  = sqrt(x * x + y * y + z * z);
    const double th = acos(z / r);
    const double fi = atan2(y, x);

    double h0[H0d];
    #pragma unroll
    for (int i = 0; i < H0d; i++) {
        double a = x * W0[i] + y * W0[H0d + i] + z * W0[2 * H0d + i]
                 + th * W0[3 * H0d + i] + fi * W0[4 * H0d + i];
        a = (a - MU0[i]) * RS0[i] + BE0[i];
        h0[i] = a > 0.0 ? a : 0.0;
    }
    float* o = h1T + (size_t)(p >> 13) * (H1d * Md) + (p & (Md - 1));
    for (int jc = 0; jc < 32; jc += 2) {
        double a0 = 0.0, a1 = 0.0;
        #pragma unroll
        for (int i = 0; i < H0d; i++) {
            double h = h0[i];
            a0 += h * W1[i * 32 + jc];
            a1 += h * W1[i * 32 + jc + 1];
        }
        a0 = (a0 - MU1[jc]) * RS1[jc] + BE1[jc];             a0 = a0 > 0.0 ? a0 : 0.0;
        a1 = (a1 - MU1[jc + 1]) * RS1[jc + 1] + BE1[jc + 1]; a1 = a1 > 0.0 ? a1 : 0.0;
        o[(size_t)(j0 + jc) * Md]     = (float)a0;
        o[(size_t)(j0 + jc + 1) * Md] = (float)a1;
    }
}

// ---------------------------------------------------------------------------
// K2: f32 GEMM, 128x128 tile, 8x8 per thread, BK=32 x 4 steps.
// [round-12-verified verbatim]
// ---------------------------------------------------------------------------
__global__ __launch_bounds__(256, 4) void k2_gemm(
    const float* __restrict__ h1T,
    const float* __restrict__ w2,
    float* __restrict__ logits)
{
    __shared__ float As[32][128];            // 16 KB
    __shared__ float Bs[32][128];            // 16 KB
    const int bx = blockIdx.x, b = blockIdx.y;
    const int mtile = bx & 63, stile = bx >> 6;   // mtile fast: same-A blocks on one XCD
    const int m0 = mtile * 128, s0 = stile * 128;
    const int t = threadIdx.x;
    const int tm = t & 15, tn = t >> 4;

    float acc[8][8] = {};

    for (int kt = 0; kt < 4; kt++) {
        const float* Ag = h1T + ((size_t)b * H1d + kt * 32) * Md + m0;
        const float* Bg = w2 + (size_t)(kt * 32) * Sd + s0;
        #pragma unroll
        for (int i = 0; i < 4; i++) {
            int idx = t + i * 256;
            int kk = idx >> 5, c = idx & 31;
            *(float4*)&As[kk][c * 4] = *(const float4*)&Ag[(size_t)kk * Md + c * 4];
            *(float4*)&Bs[kk][c * 4] = *(const float4*)&Bg[(size_t)kk * Sd + c * 4];
        }
        __syncthreads();

        #pragma unroll 8
        for (int k = 0; k < 32; k++) {
            float a_[8], b_[8];
            *(float4*)&a_[0] = *(const float4*)&As[k][tm * 4];
            *(float4*)&a_[4] = *(const float4*)&As[k][64 + tm * 4];
            *(float4*)&b_[0] = *(const float4*)&Bs[k][tn * 4];
            *(float4*)&b_[4] = *(const float4*)&Bs[k][64 + tn * 4];
            #pragma unroll
            for (int si = 0; si < 8; si++)
                #pragma unroll
                for (int mi = 0; mi < 8; mi++)
                    acc[si][mi] += b_[si] * a_[mi];
        }
        __syncthreads();
    }

    #pragma unroll
    for (int si = 0; si < 8; si++) {
        int s = s0 + (si >> 2) * 64 + tn * 4 + (si & 3);
        float* row = logits + ((size_t)b * Sd + s) * Md + m0;
        *(float4*)&row[tm * 4]      = make_float4(acc[si][0], acc[si][1], acc[si][2], acc[si][3]);
        *(float4*)&row[64 + tm * 4] = make_float4(acc[si][4], acc[si][5], acc[si][6], acc[si][7]);
    }
}

// ---------------------------------------------------------------------------
// K3 (fused): selection + one-hot + gather, one block per (b,s) row.
// TWO-PASS lazy-sigmoid (round-13 logic, restructured for low VGPR):
//   Pass A: stream L+G once, keep only slot-max (bitonic -> T, logit domain)
//           and gumbel max (-> gthr). ~2 live registers, full MLP.
//   Pass B: re-read L+G (L2-hot: block re-reads its own 64KB), collect
//           gumbel candidates (g >= gthr), top-k candidates (logit >= T,
//           expf ONLY on ~150 cands), and ncmax. Round-13-verified logic;
//           re-read values are bit-identical (same memory, deterministic).
// Downstream (gumbel <=32 resolve + full-scan fallback, rank-count, 4-ulp
// exclusion-safety check, full-expf iterative fallback) is round-13 verbatim,
// with fallbacks rebuilding arrays from an L2 reload.
// ---------------------------------------------------------------------------
__global__ __launch_bounds__(256) void k3_fused(
    float* __restrict__ logits,              // row r read, then overwritten with Qg
    const float* __restrict__ gumbel,
    const float* __restrict__ coord,
    const float* __restrict__ feat,
    float* __restrict__ out)
{
    const int r = blockIdx.x;                // 0..4095
    const int b = r >> 10;
    const int t = threadIdx.x;
    const int lane = t & 63, wav = t >> 6;
    const float4* L4 = (const float4*)(logits + (size_t)r * Md);
    const float4* G4 = (const float4*)(gumbel + (size_t)r * Md);

    __shared__ unsigned long long wred[2][4];
    __shared__ unsigned long long ck[CAP];
    __shared__ unsigned swT[4], swG[4], swNC[4];
    __shared__ int cnt, gcnt;
    __shared__ unsigned minQ32;
    __shared__ unsigned long long gkey;
    __shared__ int order[32];
    __shared__ int   gm_lds[32];
    __shared__ float gl_lds[32], gg_lds[32];

    // ---- pass A: streaming reduces only ----
    unsigned pm = 0u, gmx = 0u;
    #pragma unroll
    for (int j = 0; j < 8; j++) {
        float4 v = L4[j * 256 + t];
        float4 g = G4[j * 256 + t];
        pm  = max(pm,  max(max(f2u(v.x), f2u(v.y)), max(f2u(v.z), f2u(v.w))));
        gmx = max(gmx, max(max(f2u(g.x), f2u(g.y)), max(f2u(g.z), f2u(g.w))));
    }
    #pragma unroll
    for (int o = 32; o > 0; o >>= 1) gmx = max(gmx, (unsigned)__shfl_xor(gmx, o));
    unsigned v = pm;
    #pragma unroll
    for (int k = 2; k <= 64; k <<= 1) {
        #pragma unroll
        for (int j = k >> 1; j > 0; j >>= 1) {
            unsigned o = __shfl_xor(v, j);
            bool up = ((lane & k) == 0);
            bool lower = ((lane & j) == 0);
            unsigned mn = min(v, o), mx = max(v, o);
            v = (lower == up) ? mn : mx;     // ascending by lane after final pass
        }
    }
    unsigned tw = __shfl(v, 32);             // 32nd largest of the wave's lane maxima
    if (lane == 0) { swT[wav] = tw; swG[wav] = gmx; }
    if (t == 0) { cnt = 0; gcnt = 0; minQ32 = 0xFFFFFFFFu; gkey = 0ull; }
    __syncthreads();                         // B1
    const unsigned T = max(max(swT[0], swT[1]), max(swT[2], swT[3]));
    const float gthr = u2f(max(max(swG[0], swG[1]), max(swG[2], swG[3]))) - 1.01f;

    // ---- pass B: reload (L2-hot), collect candidates ----
    unsigned ncmax = 0u;
    #pragma unroll
    for (int j = 0; j < 8; j++) {
        float4 vv = L4[j * 256 + t];
        float4 gg = G4[j * 256 + t];
        #pragma unroll
        for (int c = 0; c < 4; c++) {
            const float lx = ((const float*)&vv)[c];
            const float gx = ((const float*)&gg)[c];
            const int m = j * 1024 + t * 4 + c;
            if (gx >= gthr) {
                int gp = atomicAdd(&gcnt, 1);
                if (gp < 32) { gm_lds[gp] = m; gl_lds[gp] = lx; gg_lds[gp] = gx; }
            }
            unsigned ul = f2u(lx);
            if (ul >= T) {
                int pos = atomicAdd(&cnt, 1);
                if (pos < CAP) {
                    float q = 1.0f / (1.0f + expf(-lx));   // exact Q key (libm)
                    ck[pos] = ((unsigned long long)f2u(q) << 32) | (unsigned)(Md - 1 - m);
                }
            } else {
                ncmax = max(ncmax, ul);
            }
        }
    }
    #pragma unroll
    for (int o = 32; o > 0; o >>= 1) ncmax = max(ncmax, (unsigned)__shfl_xor(ncmax, o));
    if (lane == 0) swNC[wav] = ncmax;
    __syncthreads();                         // B2: cnt, gcnt, ck, lists, swNC
    const int n = cnt, ng = gcnt;

    // ---- gumbel argmax resolve ----
    if (ng <= 32) {
        if (t < ng) {
            float q = 1.0f / (1.0f + expf(-gl_lds[t]));
            unsigned long long k = ((unsigned long long)f2u(q + gg_lds[t]) << 32)
                                 | (unsigned)(Md - 1 - gm_lds[t]);
            atomicMax(&gkey, k);
        }
    } else {
        // fallback: full scan (round-9-verified formula), reload from L2
        unsigned long long kb = 0ull;
        #pragma unroll
        for (int j = 0; j < 8; j++) {
            float4 vv = L4[j * 256 + t];
            float4 gg = G4[j * 256 + t];
            #pragma unroll
            for (int c = 0; c < 4; c++) {
                const int m = j * 1024 + t * 4 + c;
                float q = 1.0f / (1.0f + expf(-((const float*)&vv)[c]));
                unsigned long long k = ((unsigned long long)f2u(q + ((const float*)&gg)[c]) << 32)
                                     | (unsigned)(Md - 1 - m);
                if (k > kb) kb = k;
            }
        }
        #pragma unroll
        for (int o = 32; o > 0; o >>= 1) {
            unsigned long long ok = __shfl_down(kb, o);
            if (ok > kb) kb = ok;
        }
        if (lane == 0) atomicMax(&gkey, kb);
    }

    // ---- top-k fast path: rank-count on exact Q keys ----
    const bool tryfast = (n >= 32 && n <= CAP);
    if (tryfast) {
        for (int j2 = t; j2 < n; j2 += 256) {
            unsigned long long mine = ck[j2];
            int rk = 0;
            for (int i2 = 0; i2 < n; i2++) rk += (ck[i2] > mine) ? 1 : 0;
            if (rk < 32) {
                order[rk] = Md - 1 - (int)(mine & 0xFFFFFFFFull);
                atomicMin(&minQ32, (unsigned)(mine >> 32));
            }
        }
    }
    __syncthreads();                         // B3: gkey, order, minQ32
    const int am = Md - 1 - (int)(gkey & 0xFFFFFFFFull);

    // ---- exclusion-safety verification (block-uniform) ----
    bool safe = false;
    if (tryfast) {
        const unsigned xnc = max(max(swNC[0], swNC[1]), max(swNC[2], swNC[3]));
        float xf = u2f(xnc);                 // max non-candidate logit
        unsigned qnc = f2u(1.0f / (1.0f + expf(-xf)));
        safe = (qnc + 4u) < minQ32;          // 4-ulp margin
    }

    if (!safe) {
        // ---- verified full fallback: Q-domain iterative extraction ----
        // rebuild uq from an L2 reload (bit-identical values)
        unsigned uq[32];
        #pragma unroll
        for (int j = 0; j < 8; j++) {
            float4 vv = L4[j * 256 + t];
            #pragma unroll
            for (int c = 0; c < 4; c++)
                uq[j * 4 + c] = f2u(1.0f / (1.0f + expf(-((const float*)&vv)[c])));
        }
        for (int round = 0; round < 32; round++) {
            unsigned bu = 0u; int bi = 0;
            #pragma unroll
            for (int i = 0; i < 32; i++)
                if (uq[i] > bu) { bu = uq[i]; bi = i; }
            int bm = (bi >> 2) * 1024 + t * 4 + (bi & 3);
            unsigned long long key =
                ((unsigned long long)bu << 32) | (unsigned)(Md - 1 - bm);
            #pragma unroll
            for (int o = 32; o > 0; o >>= 1) {
                unsigned long long other = __shfl_down(key, o);
                if (other > key) key = other;
            }
            const int p = round & 1;
            if (lane == 0) wred[p][wav] = key;
            __syncthreads();
            unsigned long long best = wred[p][0];
            if (wred[p][1] > best) best = wred[p][1];
            if (wred[p][2] > best) best = wred[p][2];
            if (wred[p][3] > best) best = wred[p][3];
            const int m_win = Md - 1 - (int)(best & 0xFFFFFFFFull);
            if (((m_win >> 2) & 255) == t)
                uq[(m_win >> 10) * 4 + (m_win & 3)] = 0u;
            if (t == 0) order[round] = m_win;
        }
    }
    __syncthreads();                         // B4: order[] final

    // ---- outputs (verified verbatim) ----
    {
        const int q4 = am >> 2;
        float4* row = (float4*)(logits + (size_t)r * Md);
        #pragma unroll
        for (int i = 0; i < 8; i++) {
            int idx = i * 256 + t;
            float4 vv = make_float4(0.f, 0.f, 0.f, 0.f);
            if (idx == q4) ((float*)&vv)[am & 3] = 1.0f;
            row[idx] = vv;
        }
    }
    if (t < 3)
        out[OFF_SP + (size_t)r * 3 + t] = coord[((size_t)b * Md + am) * 3 + t];
    if (t >= 32 && t < 128) {
        int e = t - 32;                      // 0..95
        int nn = e / 3, c = e - nn * 3;
        out[OFF_GP + (size_t)r * 96 + e] = coord[((size_t)b * Md + order[nn]) * 3 + c];
    }
    const float4* F4  = (const float4*)feat;          // feat row = 16 float4
    float4* SF4 = (float4*)(out + OFF_SF);
    float4* GF4 = (float4*)(out + OFF_GF);
    if (t < 16) {
        float4 fv = F4[((size_t)b * Md + am) * 16 + t];
        SF4[(size_t)r * 16 + t]  = fv;       // sampled_feature
        GF4[(size_t)r * 512 + t] = fv;       // grouped_feature[.,.,0,:]
    }
    for (int e4 = 16 + t; e4 < 512; e4 += 256) {
        int nn = e4 >> 4, d4 = e4 & 15;
        GF4[(size_t)r * 512 + e4] = F4[((size_t)b * Md + order[nn]) * 16 + d4];
    }
}

// ---------------------------------------------------------------------------
extern "C" void kernel_launch(void* const* d_in, const int* in_sizes, int n_in,
                              void* d_out, int out_size, void* d_ws, size_t ws_size,
                              hipStream_t stream)
{
    (void)in_sizes; (void)n_in; (void)out_size; (void)d_ws; (void)ws_size;
    const float* coord = (const float*)d_in[0];
    const float* feat  = (const float*)d_in[1];
    const float* gum   = (const float*)d_in[2];
    const float* w0    = (const float*)d_in[3];
    const float* g0    = (const float*)d_in[4];
    const float* be0   = (const float*)d_in[5];
    const float* mu0   = (const float*)d_in[6];
    const float* va0   = (const float*)d_in[7];
    const float* w1    = (const float*)d_in[8];
    const float* g1    = (const float*)d_in[9];
    const float* be1   = (const float*)d_in[10];
    const float* va1_  = (const float*)d_in[12];
    const float* mu1   = (const float*)d_in[11];
    const float* w2    = (const float*)d_in[13];

    float*  out    = (float*)d_out;
    float*  h1T    = out + OFF_GF;              // f32 h1T scratch (overwritten by k3 gather)
    float*  logits = out + OFF_QG;              // f32 logits -> Qg one-hot

    k1_mlp   <<<dim3(512),     dim3(256), 0, stream>>>(coord, w0, g0, be0, mu0, va0,
                                                       w1, g1, be1, mu1, va1_, h1T);
    k2_gemm  <<<dim3(512, 4),  dim3(256), 0, stream>>>(h1T, w2, logits);
    k3_fused <<<dim3(4096),    dim3(256), 0, stream>>>(logits, gum, coord, feat, out);
}

// Round 15
// 227.025 us; speedup vs baseline: 1.0795x; 1.0795x over previous
//
#include <hip/hip_runtime.h>
#include <math.h>

// Problem constants
#define Bd   4
#define Md   8192
#define Dd   64
#define Sd   1024
#define H0d  32
#define H1d  128

// d_out layout (float offsets), return order:
// sampled_points (B,S,3) | grouped_points (B,S,32,3) | sampled_feature (B,S,64)
// | grouped_feature (B,S,32,64) | Qg (B,S,M)
#define OFF_SP 0
#define OFF_GP 12288
#define OFF_SF 405504
#define OFF_GF 667648          // holds f32 h1T scratch [b][k][m] (16.8MB) until k3 overwrites
#define OFF_QG 9056256         // holds f32 logits [B][S][M] until one-hot overwrite

#define CAP 512                // candidate cap (expected n ~150)

// order-preserving float -> sortable u32, and exact inverse
__device__ __forceinline__ unsigned f2u(float f) {
    unsigned v = __float_as_uint(f);
    return (v & 0x80000000u) ? ~v : (v | 0x80000000u);
}
__device__ __forceinline__ float u2f(unsigned u) {
    return __uint_as_float((u & 0x80000000u) ? (u ^ 0x80000000u) : ~u);
}

// ---------------------------------------------------------------------------
// K1: per-point MLP (f64 internal math, f32 output), h1T[b][k][m].
// 4-way j-split, 512 blocks — bitwise-identical h1T, verified rounds 10-14.
// ---------------------------------------------------------------------------
__global__ __launch_bounds__(256) void k1_mlp(
    const float* __restrict__ coord,
    const float* __restrict__ w0,
    const float* __restrict__ g0, const float* __restrict__ be0,
    const float* __restrict__ mu0, const float* __restrict__ va0,
    const float* __restrict__ w1,
    const float* __restrict__ g1, const float* __restrict__ be1,
    const float* __restrict__ mu1, const float* __restrict__ va1,
    float* __restrict__ h1T)
{
    const int jg = blockIdx.x & 3;           // j-range [jg*32, jg*32+32)
    const int j0 = jg * 32;
    __shared__ double W1[H0d * 32];
    __shared__ double W0[5 * H0d];
    __shared__ double MU0[H0d], RS0[H0d], BE0[H0d];
    __shared__ double MU1[32], RS1[32], BE1[32];
    const int t = threadIdx.x;
    for (int e = t; e < H0d * 32; e += 256) {
        int i = e >> 5, jc = e & 31;
        W1[e] = (double)w1[i * H1d + j0 + jc];
    }
    if (t < 5 * H0d) W0[t] = (double)w0[t];
    if (t < H0d) {
        MU0[t] = (double)mu0[t];
        RS0[t] = (double)g0[t] / sqrt((double)va0[t] + 1e-5);
        BE0[t] = (double)be0[t];
    }
    if (t >= 192 && t < 224) {
        int j = t - 192;
        MU1[j] = (double)mu1[j0 + j];
        RS1[j] = (double)g1[j0 + j] / sqrt((double)va1[j0 + j] + 1e-5);
        BE1[j] = (double)be1[j0 + j];
    }
    __syncthreads();

    const int p = (blockIdx.x >> 2) * 256 + t;   // 0..32767  (= b*M + m)
    const double x = (double)coord[p * 3 + 0];
    const double y = (double)coord[p * 3 + 1];
    const double z = (double)coord[p * 3 + 2];
    const double r  = sqrt(x * x + y * y + z * z);
    const double th = acos(z / r);
    const double fi = atan2(y, x);

    double h0[H0d];
    #pragma unroll
    for (int i = 0; i < H0d; i++) {
        double a = x * W0[i] + y * W0[H0d + i] + z * W0[2 * H0d + i]
                 + th * W0[3 * H0d + i] + fi * W0[4 * H0d + i];
        a = (a - MU0[i]) * RS0[i] + BE0[i];
        h0[i] = a > 0.0 ? a : 0.0;
    }
    float* o = h1T + (size_t)(p >> 13) * (H1d * Md) + (p & (Md - 1));
    for (int jc = 0; jc < 32; jc += 2) {
        double a0 = 0.0, a1 = 0.0;
        #pragma unroll
        for (int i = 0; i < H0d; i++) {
            double h = h0[i];
            a0 += h * W1[i * 32 + jc];
            a1 += h * W1[i * 32 + jc + 1];
        }
        a0 = (a0 - MU1[jc]) * RS1[jc] + BE1[jc];             a0 = a0 > 0.0 ? a0 : 0.0;
        a1 = (a1 - MU1[jc + 1]) * RS1[jc + 1] + BE1[jc + 1]; a1 = a1 > 0.0 ? a1 : 0.0;
        o[(size_t)(j0 + jc) * Md]     = (float)a0;
        o[(size_t)(j0 + jc + 1) * Md] = (float)a1;
    }
}

// ---------------------------------------------------------------------------
// K2: f32 GEMM, 128x128 tile, 8x8 per thread, BK=32 x 4 steps.
// [round-12-verified verbatim]
// ---------------------------------------------------------------------------
__global__ __launch_bounds__(256, 4) void k2_gemm(
    const float* __restrict__ h1T,
    const float* __restrict__ w2,
    float* __restrict__ logits)
{
    __shared__ float As[32][128];            // 16 KB
    __shared__ float Bs[32][128];            // 16 KB
    const int bx = blockIdx.x, b = blockIdx.y;
    const int mtile = bx & 63, stile = bx >> 6;   // mtile fast: same-A blocks on one XCD
    const int m0 = mtile * 128, s0 = stile * 128;
    const int t = threadIdx.x;
    const int tm = t & 15, tn = t >> 4;

    float acc[8][8] = {};

    for (int kt = 0; kt < 4; kt++) {
        const float* Ag = h1T + ((size_t)b * H1d + kt * 32) * Md + m0;
        const float* Bg = w2 + (size_t)(kt * 32) * Sd + s0;
        #pragma unroll
        for (int i = 0; i < 4; i++) {
            int idx = t + i * 256;
            int kk = idx >> 5, c = idx & 31;
            *(float4*)&As[kk][c * 4] = *(const float4*)&Ag[(size_t)kk * Md + c * 4];
            *(float4*)&Bs[kk][c * 4] = *(const float4*)&Bg[(size_t)kk * Sd + c * 4];
        }
        __syncthreads();

        #pragma unroll 8
        for (int k = 0; k < 32; k++) {
            float a_[8], b_[8];
            *(float4*)&a_[0] = *(const float4*)&As[k][tm * 4];
            *(float4*)&a_[4] = *(const float4*)&As[k][64 + tm * 4];
            *(float4*)&b_[0] = *(const float4*)&Bs[k][tn * 4];
            *(float4*)&b_[4] = *(const float4*)&Bs[k][64 + tn * 4];
            #pragma unroll
            for (int si = 0; si < 8; si++)
                #pragma unroll
                for (int mi = 0; mi < 8; mi++)
                    acc[si][mi] += b_[si] * a_[mi];
        }
        __syncthreads();
    }

    #pragma unroll
    for (int si = 0; si < 8; si++) {
        int s = s0 + (si >> 2) * 64 + tn * 4 + (si & 3);
        float* row = logits + ((size_t)b * Sd + s) * Md + m0;
        *(float4*)&row[tm * 4]      = make_float4(acc[si][0], acc[si][1], acc[si][2], acc[si][3]);
        *(float4*)&row[64 + tm * 4] = make_float4(acc[si][4], acc[si][5], acc[si][6], acc[si][7]);
    }
}

// ---------------------------------------------------------------------------
// K3 (fused): selection + one-hot + gather, one block per (b,s) row.
// LDS-stash lazy-sigmoid (round-13/14-verified selection logic):
//   Pass A (single HBM pass): stream L+G; write f2u(L) into LDS (32KB);
//     keep graw[32] in regs; reduce slot-max (bitonic -> T, logit domain)
//     and gumbel max (-> gthr).
//   Pass B (LDS only): per-thread re-read own f2u(L) from LDS; collect
//     gumbel candidates (g >= gthr) and top-k candidates (logit >= T,
//     expf ONLY on ~150 cands); track ncmax.
// Downstream verbatim from verified rounds: gumbel <=32 resolve (+full-scan
// fallback from regs/LDS), rank-count on exact Q keys, 4-ulp exclusion-
// safety check, full-expf iterative fallback rebuilt from LDS.
// No HBM re-read anywhere; u2f(f2u(x)) == x exactly -> bit-identical keys.
// ---------------------------------------------------------------------------
__global__ __launch_bounds__(256) void k3_fused(
    float* __restrict__ logits,              // row r read, then overwritten with Qg
    const float* __restrict__ gumbel,
    const float* __restrict__ coord,
    const float* __restrict__ feat,
    float* __restrict__ out)
{
    const int r = blockIdx.x;                // 0..4095
    const int b = r >> 10;
    const int t = threadIdx.x;
    const int lane = t & 63, wav = t >> 6;
    const float4* L4 = (const float4*)(logits + (size_t)r * Md);
    const float4* G4 = (const float4*)(gumbel + (size_t)r * Md);

    __shared__ unsigned Lu[Md];              // 32 KB: f2u(logit) per element
    __shared__ unsigned long long wred[2][4];
    __shared__ unsigned long long ck[CAP];
    __shared__ unsigned swT[4], swG[4], swNC[4];
    __shared__ int cnt, gcnt;
    __shared__ unsigned minQ32;
    __shared__ unsigned long long gkey;
    __shared__ int order[32];
    __shared__ int   gm_lds[32];
    __shared__ float gl_lds[32], gg_lds[32];

    // ---- pass A: single HBM stream; LDS stash + reduces ----
    float graw[32];
    unsigned pm = 0u, gmx = 0u;
    #pragma unroll
    for (int j = 0; j < 8; j++) {
        float4 v = L4[j * 256 + t];
        float4 g = G4[j * 256 + t];
        uint4 uv = make_uint4(f2u(v.x), f2u(v.y), f2u(v.z), f2u(v.w));
        *(uint4*)&Lu[j * 1024 + t * 4] = uv;
        pm = max(pm, max(max(uv.x, uv.y), max(uv.z, uv.w)));
        graw[j * 4 + 0] = g.x; graw[j * 4 + 1] = g.y;
        graw[j * 4 + 2] = g.z; graw[j * 4 + 3] = g.w;
        gmx = max(gmx, max(max(f2u(g.x), f2u(g.y)), max(f2u(g.z), f2u(g.w))));
    }
    #pragma unroll
    for (int o = 32; o > 0; o >>= 1) gmx = max(gmx, (unsigned)__shfl_xor(gmx, o));
    unsigned v = pm;
    #pragma unroll
    for (int k = 2; k <= 64; k <<= 1) {
        #pragma unroll
        for (int j = k >> 1; j > 0; j >>= 1) {
            unsigned o = __shfl_xor(v, j);
            bool up = ((lane & k) == 0);
            bool lower = ((lane & j) == 0);
            unsigned mn = min(v, o), mx = max(v, o);
            v = (lower == up) ? mn : mx;     // ascending by lane after final pass
        }
    }
    unsigned tw = __shfl(v, 32);             // 32nd largest of the wave's lane maxima
    if (lane == 0) { swT[wav] = tw; swG[wav] = gmx; }
    if (t == 0) { cnt = 0; gcnt = 0; minQ32 = 0xFFFFFFFFu; gkey = 0ull; }
    __syncthreads();                         // B1: swT/swG/Lu/cnt
    const unsigned T = max(max(swT[0], swT[1]), max(swT[2], swT[3]));
    const float gthr = u2f(max(max(swG[0], swG[1]), max(swG[2], swG[3]))) - 1.01f;

    // ---- pass B: LDS-only candidate collection ----
    unsigned ncmax = 0u;
    #pragma unroll
    for (int j = 0; j < 8; j++) {
        uint4 uv = *(const uint4*)&Lu[j * 1024 + t * 4];
        #pragma unroll
        for (int c = 0; c < 4; c++) {
            const unsigned ul = ((const unsigned*)&uv)[c];
            const float gx = graw[j * 4 + c];
            const int m = j * 1024 + t * 4 + c;
            if (gx >= gthr) {
                int gp = atomicAdd(&gcnt, 1);
                if (gp < 32) { gm_lds[gp] = m; gl_lds[gp] = u2f(ul); gg_lds[gp] = gx; }
            }
            if (ul >= T) {
                int pos = atomicAdd(&cnt, 1);
                if (pos < CAP) {
                    float q = 1.0f / (1.0f + expf(-u2f(ul)));   // exact Q key (libm)
                    ck[pos] = ((unsigned long long)f2u(q) << 32) | (unsigned)(Md - 1 - m);
                }
            } else {
                ncmax = max(ncmax, ul);
            }
        }
    }
    #pragma unroll
    for (int o = 32; o > 0; o >>= 1) ncmax = max(ncmax, (unsigned)__shfl_xor(ncmax, o));
    if (lane == 0) swNC[wav] = ncmax;
    __syncthreads();                         // B2: cnt, gcnt, ck, lists, swNC
    const int n = cnt, ng = gcnt;

    // ---- gumbel argmax resolve ----
    if (ng <= 32) {
        if (t < ng) {
            float q = 1.0f / (1.0f + expf(-gl_lds[t]));
            unsigned long long k = ((unsigned long long)f2u(q + gg_lds[t]) << 32)
                                 | (unsigned)(Md - 1 - gm_lds[t]);
            atomicMax(&gkey, k);
        }
    } else {
        // fallback: full scan (verified formula), inputs from regs + LDS
        unsigned long long kb = 0ull;
        #pragma unroll
        for (int j = 0; j < 8; j++) {
            uint4 uv = *(const uint4*)&Lu[j * 1024 + t * 4];
            #pragma unroll
            for (int c = 0; c < 4; c++) {
                const int m = j * 1024 + t * 4 + c;
                float q = 1.0f / (1.0f + expf(-u2f(((const unsigned*)&uv)[c])));
                unsigned long long k = ((unsigned long long)f2u(q + graw[j * 4 + c]) << 32)
                                     | (unsigned)(Md - 1 - m);
                if (k > kb) kb = k;
            }
        }
        #pragma unroll
        for (int o = 32; o > 0; o >>= 1) {
            unsigned long long ok = __shfl_down(kb, o);
            if (ok > kb) kb = ok;
        }
        if (lane == 0) atomicMax(&gkey, kb);
    }

    // ---- top-k fast path: rank-count on exact Q keys ----
    const bool tryfast = (n >= 32 && n <= CAP);
    if (tryfast) {
        for (int j2 = t; j2 < n; j2 += 256) {
            unsigned long long mine = ck[j2];
            int rk = 0;
            for (int i2 = 0; i2 < n; i2++) rk += (ck[i2] > mine) ? 1 : 0;
            if (rk < 32) {
                order[rk] = Md - 1 - (int)(mine & 0xFFFFFFFFull);
                atomicMin(&minQ32, (unsigned)(mine >> 32));
            }
        }
    }
    __syncthreads();                         // B3: gkey, order, minQ32
    const int am = Md - 1 - (int)(gkey & 0xFFFFFFFFull);

    // ---- exclusion-safety verification (block-uniform) ----
    bool safe = false;
    if (tryfast) {
        const unsigned xnc = max(max(swNC[0], swNC[1]), max(swNC[2], swNC[3]));
        float xf = u2f(xnc);                 // max non-candidate logit
        unsigned qnc = f2u(1.0f / (1.0f + expf(-xf)));
        safe = (qnc + 4u) < minQ32;          // 4-ulp margin
    }

    if (!safe) {
        // ---- verified full fallback: Q-domain iterative extraction ----
        // rebuild uq from LDS (bit-identical values, no HBM)
        unsigned uq[32];
        #pragma unroll
        for (int j = 0; j < 8; j++) {
            uint4 uv = *(const uint4*)&Lu[j * 1024 + t * 4];
            #pragma unroll
            for (int c = 0; c < 4; c++)
                uq[j * 4 + c] = f2u(1.0f / (1.0f + expf(-u2f(((const unsigned*)&uv)[c]))));
        }
        for (int round = 0; round < 32; round++) {
            unsigned bu = 0u; int bi = 0;
            #pragma unroll
            for (int i = 0; i < 32; i++)
                if (uq[i] > bu) { bu = uq[i]; bi = i; }
            int bm = (bi >> 2) * 1024 + t * 4 + (bi & 3);
            unsigned long long key =
                ((unsigned long long)bu << 32) | (unsigned)(Md - 1 - bm);
            #pragma unroll
            for (int o = 32; o > 0; o >>= 1) {
                unsigned long long other = __shfl_down(key, o);
                if (other > key) key = other;
            }
            const int p = round & 1;
            if (lane == 0) wred[p][wav] = key;
            __syncthreads();
            unsigned long long best = wred[p][0];
            if (wred[p][1] > best) best = wred[p][1];
            if (wred[p][2] > best) best = wred[p][2];
            if (wred[p][3] > best) best = wred[p][3];
            const int m_win = Md - 1 - (int)(best & 0xFFFFFFFFull);
            if (((m_win >> 2) & 255) == t)
                uq[(m_win >> 10) * 4 + (m_win & 3)] = 0u;
            if (t == 0) order[round] = m_win;
        }
    }
    __syncthreads();                         // B4: order[] final

    // ---- outputs (verified verbatim) ----
    {
        const int q4 = am >> 2;
        float4* row = (float4*)(logits + (size_t)r * Md);
        #pragma unroll
        for (int i = 0; i < 8; i++) {
            int idx = i * 256 + t;
            float4 vv = make_float4(0.f, 0.f, 0.f, 0.f);
            if (idx == q4) ((float*)&vv)[am & 3] = 1.0f;
            row[idx] = vv;
        }
    }
    if (t < 3)
        out[OFF_SP + (size_t)r * 3 + t] = coord[((size_t)b * Md + am) * 3 + t];
    if (t >= 32 && t < 128) {
        int e = t - 32;                      // 0..95
        int nn = e / 3, c = e - nn * 3;
        out[OFF_GP + (size_t)r * 96 + e] = coord[((size_t)b * Md + order[nn]) * 3 + c];
    }
    const float4* F4  = (const float4*)feat;          // feat row = 16 float4
    float4* SF4 = (float4*)(out + OFF_SF);
    float4* GF4 = (float4*)(out + OFF_GF);
    if (t < 16) {
        float4 fv = F4[((size_t)b * Md + am) * 16 + t];
        SF4[(size_t)r * 16 + t]  = fv;       // sampled_feature
        GF4[(size_t)r * 512 + t] = fv;       // grouped_feature[.,.,0,:]
    }
    for (int e4 = 16 + t; e4 < 512; e4 += 256) {
        int nn = e4 >> 4, d4 = e4 & 15;
        GF4[(size_t)r * 512 + e4] = F4[((size_t)b * Md + order[nn]) * 16 + d4];
    }
}

// ---------------------------------------------------------------------------
extern "C" void kernel_launch(void* const* d_in, const int* in_sizes, int n_in,
                              void* d_out, int out_size, void* d_ws, size_t ws_size,
                              hipStream_t stream)
{
    (void)in_sizes; (void)n_in; (void)out_size; (void)d_ws; (void)ws_size;
    const float* coord = (const float*)d_in[0];
    const float* feat  = (const float*)d_in[1];
    const float* gum   = (const float*)d_in[2];
    const float* w0    = (const float*)d_in[3];
    const float* g0    = (const float*)d_in[4];
    const float* be0   = (const float*)d_in[5];
    const float* mu0   = (const float*)d_in[6];
    const float* va0   = (const float*)d_in[7];
    const float* w1    = (const float*)d_in[8];
    const float* g1    = (const float*)d_in[9];
    const float* be1   = (const float*)d_in[10];
    const float* mu1   = (const float*)d_in[11];
    const float* va1   = (const float*)d_in[12];
    const float* w2    = (const float*)d_in[13];

    float*  out    = (float*)d_out;
    float*  h1T    = out + OFF_GF;              // f32 h1T scratch (overwritten by k3 gather)
    float*  logits = out + OFF_QG;              // f32 logits -> Qg one-hot

    k1_mlp   <<<dim3(512),     dim3(256), 0, stream>>>(coord, w0, g0, be0, mu0, va0,
                                                       w1, g1, be1, mu1, va1, h1T);
    k2_gemm  <<<dim3(512, 4),  dim3(256), 0, stream>>>(h1T, w2, logits);
    k3_fused <<<dim3(4096),    dim3(256), 0, stream>>>(logits, gum, coord, feat, out);
}

// Round 17
// 214.455 us; speedup vs baseline: 1.1428x; 1.0586x over previous
//
#include <hip/hip_runtime.h>
#include <math.h>

// Problem constants
#define Bd   4
#define Md   8192
#define Dd   64
#define Sd   1024
#define H0d  32
#define H1d  128

// d_out layout (float offsets), return order:
// sampled_points (B,S,3) | grouped_points (B,S,32,3) | sampled_feature (B,S,64)
// | grouped_feature (B,S,32,64) | Qg (B,S,M)
#define OFF_SP 0
#define OFF_GP 12288
#define OFF_SF 405504
#define OFF_GF 667648          // holds f32 h1T scratch [b][k][m] (16.8MB) until k3 overwrites
#define OFF_QG 9056256         // holds f32 logits [B][S][M] until one-hot overwrite

#define CAP 512                // candidate cap (expected n ~150)

typedef float fx4 __attribute__((ext_vector_type(4)));   // NT-store-compatible 16B vector

// order-preserving float -> sortable u32
__device__ __forceinline__ unsigned f2u(float f) {
    unsigned v = __float_as_uint(f);
    return (v & 0x80000000u) ? ~v : (v | 0x80000000u);
}

// 16B non-temporal store of a float4 value
__device__ __forceinline__ void nt_store4(float4 v, float4* dst) {
    fx4 w; w.x = v.x; w.y = v.y; w.z = v.z; w.w = v.w;
    __builtin_nontemporal_store(w, (fx4*)dst);
}

// ---------------------------------------------------------------------------
// K1: per-point MLP (f64 internal math, f32 output), h1T[b][k][m].
// 4-way j-split, 512 blocks — bitwise-identical h1T, verified rounds 10-15.
// ---------------------------------------------------------------------------
__global__ __launch_bounds__(256) void k1_mlp(
    const float* __restrict__ coord,
    const float* __restrict__ w0,
    const float* __restrict__ g0, const float* __restrict__ be0,
    const float* __restrict__ mu0, const float* __restrict__ va0,
    const float* __restrict__ w1,
    const float* __restrict__ g1, const float* __restrict__ be1,
    const float* __restrict__ mu1, const float* __restrict__ va1,
    float* __restrict__ h1T)
{
    const int jg = blockIdx.x & 3;           // j-range [jg*32, jg*32+32)
    const int j0 = jg * 32;
    __shared__ double W1[H0d * 32];
    __shared__ double W0[5 * H0d];
    __shared__ double MU0[H0d], RS0[H0d], BE0[H0d];
    __shared__ double MU1[32], RS1[32], BE1[32];
    const int t = threadIdx.x;
    for (int e = t; e < H0d * 32; e += 256) {
        int i = e >> 5, jc = e & 31;
        W1[e] = (double)w1[i * H1d + j0 + jc];
    }
    if (t < 5 * H0d) W0[t] = (double)w0[t];
    if (t < H0d) {
        MU0[t] = (double)mu0[t];
        RS0[t] = (double)g0[t] / sqrt((double)va0[t] + 1e-5);
        BE0[t] = (double)be0[t];
    }
    if (t >= 192 && t < 224) {
        int j = t - 192;
        MU1[j] = (double)mu1[j0 + j];
        RS1[j] = (double)g1[j0 + j] / sqrt((double)va1[j0 + j] + 1e-5);
        BE1[j] = (double)be1[j0 + j];
    }
    __syncthreads();

    const int p = (blockIdx.x >> 2) * 256 + t;   // 0..32767  (= b*M + m)
    const double x = (double)coord[p * 3 + 0];
    const double y = (double)coord[p * 3 + 1];
    const double z = (double)coord[p * 3 + 2];
    const double r  = sqrt(x * x + y * y + z * z);
    const double th = acos(z / r);
    const double fi = atan2(y, x);

    double h0[H0d];
    #pragma unroll
    for (int i = 0; i < H0d; i++) {
        double a = x * W0[i] + y * W0[H0d + i] + z * W0[2 * H0d + i]
                 + th * W0[3 * H0d + i] + fi * W0[4 * H0d + i];
        a = (a - MU0[i]) * RS0[i] + BE0[i];
        h0[i] = a > 0.0 ? a : 0.0;
    }
    float* o = h1T + (size_t)(p >> 13) * (H1d * Md) + (p & (Md - 1));
    for (int jc = 0; jc < 32; jc += 2) {
        double a0 = 0.0, a1 = 0.0;
        #pragma unroll
        for (int i = 0; i < H0d; i++) {
            double h = h0[i];
            a0 += h * W1[i * 32 + jc];
            a1 += h * W1[i * 32 + jc + 1];
        }
        a0 = (a0 - MU1[jc]) * RS1[jc] + BE1[jc];             a0 = a0 > 0.0 ? a0 : 0.0;
        a1 = (a1 - MU1[jc + 1]) * RS1[jc + 1] + BE1[jc + 1]; a1 = a1 > 0.0 ? a1 : 0.0;
        o[(size_t)(j0 + jc) * Md]     = (float)a0;
        o[(size_t)(j0 + jc + 1) * Md] = (float)a1;
    }
}

// ---------------------------------------------------------------------------
// K2: f32 GEMM, 128x128 tile, 8x8 per thread, BK=32 x 4 steps.
// [round-12-verified verbatim]
// ---------------------------------------------------------------------------
__global__ __launch_bounds__(256, 4) void k2_gemm(
    const float* __restrict__ h1T,
    const float* __restrict__ w2,
    float* __restrict__ logits)
{
    __shared__ float As[32][128];            // 16 KB
    __shared__ float Bs[32][128];            // 16 KB
    const int bx = blockIdx.x, b = blockIdx.y;
    const int mtile = bx & 63, stile = bx >> 6;   // mtile fast: same-A blocks on one XCD
    const int m0 = mtile * 128, s0 = stile * 128;
    const int t = threadIdx.x;
    const int tm = t & 15, tn = t >> 4;

    float acc[8][8] = {};

    for (int kt = 0; kt < 4; kt++) {
        const float* Ag = h1T + ((size_t)b * H1d + kt * 32) * Md + m0;
        const float* Bg = w2 + (size_t)(kt * 32) * Sd + s0;
        #pragma unroll
        for (int i = 0; i < 4; i++) {
            int idx = t + i * 256;
            int kk = idx >> 5, c = idx & 31;
            *(float4*)&As[kk][c * 4] = *(const float4*)&Ag[(size_t)kk * Md + c * 4];
            *(float4*)&Bs[kk][c * 4] = *(const float4*)&Bg[(size_t)kk * Sd + c * 4];
        }
        __syncthreads();

        #pragma unroll 8
        for (int k = 0; k < 32; k++) {
            float a_[8], b_[8];
            *(float4*)&a_[0] = *(const float4*)&As[k][tm * 4];
            *(float4*)&a_[4] = *(const float4*)&As[k][64 + tm * 4];
            *(float4*)&b_[0] = *(const float4*)&Bs[k][tn * 4];
            *(float4*)&b_[4] = *(const float4*)&Bs[k][64 + tn * 4];
            #pragma unroll
            for (int si = 0; si < 8; si++)
                #pragma unroll
                for (int mi = 0; mi < 8; mi++)
                    acc[si][mi] += b_[si] * a_[mi];
        }
        __syncthreads();
    }

    #pragma unroll
    for (int si = 0; si < 8; si++) {
        int s = s0 + (si >> 2) * 64 + tn * 4 + (si & 3);
        float* row = logits + ((size_t)b * Sd + s) * Md + m0;
        *(float4*)&row[tm * 4]      = make_float4(acc[si][0], acc[si][1], acc[si][2], acc[si][3]);
        *(float4*)&row[64 + tm * 4] = make_float4(acc[si][4], acc[si][5], acc[si][6], acc[si][7]);
    }
}

// ---------------------------------------------------------------------------
// K3 (fused): selection + one-hot + gather, one block per (b,s) row.
// [round-12-verified selection verbatim] Ranking domain = f32 Q =
// sigmoid(logit) via libm expf. Threshold filter + rank-count; guard falls
// back to iterative extraction.
// Only change vs round 12: Qg one-hot and grouped_feature stores are
// NON-TEMPORAL (never re-read; avoids evicting LLC-resident logits/feat).
// Values/addresses identical.
// ---------------------------------------------------------------------------
__global__ __launch_bounds__(256) void k3_fused(
    float* __restrict__ logits,              // row r read, then overwritten with Qg
    const float* __restrict__ gumbel,
    const float* __restrict__ coord,
    const float* __restrict__ feat,
    float* __restrict__ out)
{
    const int r = blockIdx.x;                // 0..4095
    const int b = r >> 10;
    const int t = threadIdx.x;
    const int lane = t & 63, wav = t >> 6;
    const float4* L4 = (const float4*)(logits + (size_t)r * Md);
    const float4* G4 = (const float4*)(gumbel + (size_t)r * Md);

    __shared__ unsigned long long wred[2][4];
    __shared__ unsigned long long ck[CAP];
    __shared__ unsigned swT[4];
    __shared__ int cnt;
    __shared__ int order[32];

    // ---- load + sigmoid + inline gumbel scan (float4, 16B/lane) ----
    unsigned uq[32];
    unsigned gbu = 0u; int gbm = 0;
    #pragma unroll
    for (int j = 0; j < 8; j++) {
        float4 v = L4[j * 256 + t];
        float4 g = G4[j * 256 + t];
        #pragma unroll
        for (int c = 0; c < 4; c++) {
            float x = ((const float*)&v)[c];
            float q = 1.0f / (1.0f + expf(-x));
            uq[j * 4 + c] = f2u(q);          // q>0 -> top bit set; 0 is a safe sentinel
            unsigned us = f2u(q + ((const float*)&g)[c]);
            if (us > gbu) { gbu = us; gbm = j * 1024 + t * 4 + c; }
        }
    }

    // ---- gumbel argmax reduce (first max -> smallest m via inverted-index key) ----
    {
        unsigned long long key = ((unsigned long long)gbu << 32) | (unsigned)(Md - 1 - gbm);
        #pragma unroll
        for (int o = 32; o > 0; o >>= 1) {
            unsigned long long other = __shfl_down(key, o);
            if (other > key) key = other;
        }
        if (lane == 0) wred[0][wav] = key;
    }
    if (t == 0) cnt = 0;
    __syncthreads();                         // B1: wred[0], cnt
    unsigned long long gbest = wred[0][0];
    if (wred[0][1] > gbest) gbest = wred[0][1];
    if (wred[0][2] > gbest) gbest = wred[0][2];
    if (wred[0][3] > gbest) gbest = wred[0][3];
    const int am = Md - 1 - (int)(gbest & 0xFFFFFFFFull);

    // ---- per-thread max, wave bitonic sort of 64 lane-maxima -> threshold T ----
    unsigned pm = 0u;
    #pragma unroll
    for (int i = 0; i < 32; i++) pm = max(pm, uq[i]);
    unsigned v = pm;
    #pragma unroll
    for (int k = 2; k <= 64; k <<= 1) {
        #pragma unroll
        for (int j = k >> 1; j > 0; j >>= 1) {
            unsigned o = __shfl_xor(v, j);
            bool up = ((lane & k) == 0);
            bool lower = ((lane & j) == 0);
            unsigned mn = min(v, o), mx = max(v, o);
            v = (lower == up) ? mn : mx;     // ascending by lane after final pass
        }
    }
    unsigned tw = __shfl(v, 32);             // asc pos 32 = 32nd largest of the wave
    if (lane == 0) swT[wav] = tw;
    __syncthreads();                         // B2: swT
    const unsigned T = max(max(swT[0], swT[1]), max(swT[2], swT[3]));

    // ---- collect candidates >= T ----
    #pragma unroll
    for (int i = 0; i < 32; i++) {
        if (uq[i] >= T) {
            int pos = atomicAdd(&cnt, 1);
            if (pos < CAP) {
                int m = (i >> 2) * 1024 + t * 4 + (i & 3);
                ck[pos] = ((unsigned long long)uq[i] << 32) | (unsigned)(Md - 1 - m);
            }
        }
    }
    __syncthreads();                         // B3: ck, cnt
    const int n = cnt;

    if (n >= 32 && n <= CAP) {
        // ---- fast path: O(n^2) rank-count ----
        for (int j2 = t; j2 < n; j2 += 256) {
            unsigned long long mine = ck[j2];
            int rk = 0;
            for (int i2 = 0; i2 < n; i2++) rk += (ck[i2] > mine) ? 1 : 0;
            if (rk < 32) order[rk] = Md - 1 - (int)(mine & 0xFFFFFFFFull);
        }
    } else {
        // ---- fallback: verified iterative extraction ----
        for (int round = 0; round < 32; round++) {
            unsigned bu = 0u; int bi = 0;
            #pragma unroll
            for (int i = 0; i < 32; i++)
                if (uq[i] > bu) { bu = uq[i]; bi = i; }
            int bm = (bi >> 2) * 1024 + t * 4 + (bi & 3);
            unsigned long long key =
                ((unsigned long long)bu << 32) | (unsigned)(Md - 1 - bm);
            #pragma unroll
            for (int o = 32; o > 0; o >>= 1) {
                unsigned long long other = __shfl_down(key, o);
                if (other > key) key = other;
            }
            const int p = round & 1;
            if (lane == 0) wred[p][wav] = key;
            __syncthreads();
            unsigned long long best = wred[p][0];
            if (wred[p][1] > best) best = wred[p][1];
            if (wred[p][2] > best) best = wred[p][2];
            if (wred[p][3] > best) best = wred[p][3];
            const int m_win = Md - 1 - (int)(best & 0xFFFFFFFFull);
            if (((m_win >> 2) & 255) == t)
                uq[(m_win >> 10) * 4 + (m_win & 3)] = 0u;
            if (t == 0) order[round] = m_win;
        }
    }
    __syncthreads();                         // B4: order[] visible

    // ---- outputs ----
    // Qg one-hot (overwrites this block's own logits row; non-temporal —
    // never re-read, keeps LLC for logits/feat)
    {
        const int q4 = am >> 2;
        float4* row = (float4*)(logits + (size_t)r * Md);
        #pragma unroll
        for (int i = 0; i < 8; i++) {
            int idx = i * 256 + t;
            float4 vv = make_float4(0.f, 0.f, 0.f, 0.f);
            if (idx == q4) ((float*)&vv)[am & 3] = 1.0f;
            nt_store4(vv, &row[idx]);
        }
    }
    if (t < 3)
        out[OFF_SP + (size_t)r * 3 + t] = coord[((size_t)b * Md + am) * 3 + t];
    if (t >= 32 && t < 128) {
        int e = t - 32;                      // 0..95
        int nn = e / 3, c = e - nn * 3;
        out[OFF_GP + (size_t)r * 96 + e] = coord[((size_t)b * Md + order[nn]) * 3 + c];
    }
    const float4* F4  = (const float4*)feat;          // feat row = 16 float4
    float4* SF4 = (float4*)(out + OFF_SF);
    float4* GF4 = (float4*)(out + OFF_GF);
    if (t < 16) {
        float4 fv = F4[((size_t)b * Md + am) * 16 + t];
        SF4[(size_t)r * 16 + t] = fv;        // sampled_feature
        nt_store4(fv, &GF4[(size_t)r * 512 + t]);     // grouped_feature[.,.,0,:]
    }
    for (int e4 = 16 + t; e4 < 512; e4 += 256) {
        int nn = e4 >> 4, d4 = e4 & 15;
        float4 fv = F4[((size_t)b * Md + order[nn]) * 16 + d4];
        nt_store4(fv, &GF4[(size_t)r * 512 + e4]);
    }
}

// ---------------------------------------------------------------------------
extern "C" void kernel_launch(void* const* d_in, const int* in_sizes, int n_in,
                              void* d_out, int out_size, void* d_ws, size_t ws_size,
                              hipStream_t stream)
{
    (void)in_sizes; (void)n_in; (void)out_size; (void)d_ws; (void)ws_size;
    const float* coord = (const float*)d_in[0];
    const float* feat  = (const float*)d_in[1];
    const float* gum   = (const float*)d_in[2];
    const float* w0    = (const float*)d_in[3];
    const float* g0    = (const float*)d_in[4];
    const float* be0   = (const float*)d_in[5];
    const float* mu0   = (const float*)d_in[6];
    const float* va0   = (const float*)d_in[7];
    const float* w1    = (const float*)d_in[8];
    const float* g1    = (const float*)d_in[9];
    const float* be1   = (const float*)d_in[10];
    const float* mu1   = (const float*)d_in[11];
    const float* va1   = (const float*)d_in[12];
    const float* w2    = (const float*)d_in[13];

    float*  out    = (float*)d_out;
    float*  h1T    = out + OFF_GF;              // f32 h1T scratch (overwritten by k3 gather)
    float*  logits = out + OFF_QG;              // f32 logits -> Qg one-hot

    k1_mlp   <<<dim3(512),     dim3(256), 0, stream>>>(coord, w0, g0, be0, mu0, va0,
                                                       w1, g1, be1, mu1, va1, h1T);
    k2_gemm  <<<dim3(512, 4),  dim3(256), 0, stream>>>(h1T, w2, logits);
    k3_fused <<<dim3(4096),    dim3(256), 0, stream>>>(logits, gum, coord, feat, out);
}